// Round 11
// baseline (2280.642 us; speedup 1.0000x reference)
//
#include <hip/hip_runtime.h>
#include <hip/hip_bf16.h>

// ---------------------------------------------------------------------------
// conv1d embed -> LSTM encoder (512 steps, B=64, H=512) -> decoder (decoupled
// h-recurrence + batched attention) -> projection.
// r27 = r26 (verified 2222us) + ctx_k encout-traffic halving: 2 blocks per
// batch (24 t each) instead of 4 (12 t) -> encout re-read 128MB -> 64MB.
// Softmax reduction arithmetic unchanged (bit-identical aw).
// Session summary of measured floors:
//  - LSTM exchange: flag protocol best of 5 designs (1452 < 1622 tagged-8B
//    < 1753 tagged-4B; XCD-local failed 3x; release fences 3x worse). Per
//    step = compute (~1300cy) + 4 agent-scope coherence legs (~700-900cy
//    each) -> ~2.8us/step. Latency floor, not BW/compute.
//  - staging GEMM: MFMA-structure-bound; pipelining under LSTM measured
//    net-negative 3x (r5/r9/r15 interference rule).
//  - attn_scores: VALU-transcendental roofline (805M v_exp_f32).
// Math order unchanged everywhere -> same absmax.
// ---------------------------------------------------------------------------

typedef short bf16x8 __attribute__((ext_vector_type(8)));
typedef float f32x4 __attribute__((ext_vector_type(4)));

static __device__ __forceinline__ float bf2f(unsigned short u){
  return __uint_as_float(((unsigned)u) << 16);
}
static __device__ __forceinline__ unsigned short f2bf(float f){
  unsigned x = __float_as_uint(f);
  return (unsigned short)((x + 0x7fffu + ((x >> 16) & 1u)) >> 16);   // RNE
}
static __device__ __forceinline__ float sigm(float x){
  return __builtin_amdgcn_rcpf(1.f + __builtin_amdgcn_exp2f(-1.44269504f*x));
}
static __device__ __forceinline__ float tanh2(float x){
  return 1.f - 2.f*__builtin_amdgcn_rcpf(1.f + __builtin_amdgcn_exp2f(2.88539008f*x));
}

static __device__ __forceinline__ unsigned ldu(const unsigned* p){
  return __hip_atomic_load(p, __ATOMIC_RELAXED, __HIP_MEMORY_SCOPE_AGENT);
}
static __device__ __forceinline__ void stu(unsigned* p, unsigned v){
  __hip_atomic_store(p, v, __ATOMIC_RELAXED, __HIP_MEMORY_SCOPE_AGENT);
}
static __device__ __forceinline__ unsigned long long ldq(const unsigned long long* p){
  return __hip_atomic_load(p, __ATOMIC_RELAXED, __HIP_MEMORY_SCOPE_AGENT);
}
static __device__ __forceinline__ void stq(unsigned long long* p, unsigned long long v){
  __hip_atomic_store(p, v, __ATOMIC_RELAXED, __HIP_MEMORY_SCOPE_AGENT);
}
#define VMWAIT() __asm__ __volatile__("s_waitcnt vmcnt(0)" ::: "memory")

// ----------------------------- merged prep kernel --------------------------
// blocks 0..511   : embed encoder (64 b x 8 chunks)
// blocks 512..575 : embed decoder (64 b x 1 chunk)
// blocks 576..    : casts (4x 1048576 + 524288 + 262144 = 4980736 elems,
//                   512 threads/block -> 9728 blocks; total 10304 blocks)
__global__ __launch_bounds__(512) void prep_k(
    const float* __restrict__ x_enc, const float* __restrict__ x_dec,
    const float* __restrict__ w_emb_e, const float* __restrict__ w_emb_d,
    unsigned short* __restrict__ encin, unsigned short* __restrict__ xs,
    const float* __restrict__ a0, const float* __restrict__ a1,
    const float* __restrict__ a2, const float* __restrict__ a3,
    const float* __restrict__ a4, const float* __restrict__ aw,
    unsigned short* __restrict__ d0, unsigned short* __restrict__ d1,
    unsigned short* __restrict__ d2, unsigned short* __restrict__ d3,
    unsigned short* __restrict__ d4,
    unsigned short* __restrict__ wh, unsigned short* __restrict__ we){
  __shared__ float wl[512*21];
  __shared__ float xl[66*7];
  const int bid = blockIdx.x, tid = threadIdx.x;
  if (bid < 576){
    const float* x; const float* wconv; unsigned short* outp;
    int Lx, l0, lcount, mode, nch, rel;
    if (bid < 512){ x = x_enc; wconv = w_emb_e; outp = encin;
                    Lx = 512; l0 = 0; lcount = 512; mode = 0; nch = 8; rel = bid; }
    else          { x = x_dec; wconv = w_emb_d; outp = xs;
                    Lx = 144; l0 = 48; lcount = 48; mode = 1; nch = 1; rel = bid - 512; }
    const int Bsz = 64;
    int b = rel / nch, ci = rel % nch;
    for (int i = tid; i < 512*21; i += 512) wl[i] = wconv[i];
    int lstart = l0 + ci*64;
    int cnt = l0 + lcount - lstart; if (cnt > 64) cnt = 64;
    int nwin = (cnt + 2) * 7;
    for (int i = tid; i < nwin; i += 512){
      int wr = i / 7, c = i % 7;
      int gl = lstart - 1 + wr;
      gl = (gl + Lx) % Lx;
      xl[i] = x[((size_t)b*Lx + gl)*7 + c];
    }
    __syncthreads();
    int o = tid;
    float fe = (float)(o & ~1);
    float div = __expf(fe * -0.0179889461f);
    const float* wrow = &wl[o*21];
    for (int li = 0; li < cnt; ++li){
      int l = lstart + li;
      float acc = 0.f;
      #pragma unroll
      for (int c = 0; c < 7; ++c)
        #pragma unroll
        for (int kk = 0; kk < 3; ++kk)
          acc += xl[(li + kk)*7 + c] * wrow[c*3 + kk];
      float arg = (float)l * div;
      acc += (o & 1) ? cosf(arg) : sinf(arg);
      size_t oi = mode ? (((size_t)b*lcount + (l - l0))*512 + o)
                       : (((size_t)l*Bsz + b)*512 + o);
      outp[oi] = f2bf(acc);
    }
    return;
  }
  int i = (bid - 576)*512 + tid;
  if (i < 1048576){ d0[i] = f2bf(a0[i]); return; }
  i -= 1048576;
  if (i < 1048576){ d1[i] = f2bf(a1[i]); return; }
  i -= 1048576;
  if (i < 1048576){ d2[i] = f2bf(a2[i]); return; }
  i -= 1048576;
  if (i < 1048576){ d3[i] = f2bf(a3[i]); return; }
  i -= 1048576;
  if (i < 524288){ d4[i] = f2bf(a4[i]); return; }
  i -= 524288;
  if (i < 262144){
    int nrow = i >> 9, k = i & 511;
    wh[i] = f2bf(aw[(size_t)nrow*1024 + k]);
    we[i] = f2bf(aw[(size_t)nrow*1024 + 512 + k]);
  }
}

// ----------------------------- bf16 NT GEMM 128x128 ------------------------
__global__ __launch_bounds__(256) void gemm_nt(const unsigned short* __restrict__ A, int lda,
    const unsigned short* __restrict__ Bw, int ldb, const float* __restrict__ bias,
    unsigned short* __restrict__ C, int ldc, int M, int N, int K){
  __shared__ __align__(16) unsigned short Asm[128*40];
  __shared__ __align__(16) unsigned short Bsm[128*40];
  const int tid = threadIdx.x;
  const int m0 = blockIdx.y * 128, n0 = blockIdx.x * 128;
  const int lane = tid & 63;
  const int wid = tid >> 6;
  const int wm = (wid >> 1) * 64, wn = (wid & 1) * 64;
  const int fr = lane & 15, q = lane >> 4;
  f32x4 acc[4][4];
  #pragma unroll
  for (int i=0;i<4;i++)
    #pragma unroll
    for(int j=0;j<4;j++) acc[i][j] = (f32x4){0.f,0.f,0.f,0.f};
  for (int k0 = 0; k0 < K; k0 += 32){
    #pragma unroll
    for (int c = 0; c < 2; ++c){
      int ch = tid + c*256;
      int r = ch >> 2, s = (ch & 3) * 8;
      *(uint4*)&Asm[r*40 + s] = *(const uint4*)&A[(size_t)(m0 + r)*lda + k0 + s];
      *(uint4*)&Bsm[r*40 + s] = *(const uint4*)&Bw[(size_t)(n0 + r)*ldb + k0 + s];
    }
    __syncthreads();
    bf16x8 af[4], bfv[4];
    #pragma unroll
    for (int i=0;i<4;i++){
      af[i]  = *(const bf16x8*)&Asm[(wm + i*16 + fr)*40 + q*8];
      bfv[i] = *(const bf16x8*)&Bsm[(wn + i*16 + fr)*40 + q*8];
    }
    #pragma unroll
    for (int i=0;i<4;i++)
      #pragma unroll
      for (int j=0;j<4;j++)
        acc[i][j] = __builtin_amdgcn_mfma_f32_16x16x32_bf16(af[i], bfv[j], acc[i][j], 0,0,0);
    __syncthreads();
  }
  #pragma unroll
  for (int i=0;i<4;i++){
    #pragma unroll
    for (int j=0;j<4;j++){
      int n = n0 + wn + j*16 + fr;
      float bv = bias ? bias[n] : 0.f;
      #pragma unroll
      for (int r=0;r<4;r++){
        int m = m0 + wm + i*16 + q*4 + r;
        C[(size_t)m*ldc + n] = f2bf(acc[i][j][r] + bv);
      }
    }
  }
}

// ------------------- merged staging GEMM + xg gemm64 -----------------------
// blocks 0..4095   : staging  encxw = encin @ wih_e^T + enc_b  [32768][2048]
// blocks 4096..4863: xg       xg    = xs    @ wih_d^T + dec_b  [3072][2048]
__global__ __launch_bounds__(256) void gemm_pair_k(
    const unsigned short* __restrict__ A1, const unsigned short* __restrict__ B1,
    const float* __restrict__ bias1, unsigned short* __restrict__ C1,
    const unsigned short* __restrict__ A2, const unsigned short* __restrict__ B2,
    const float* __restrict__ bias2, unsigned short* __restrict__ C2){
  __shared__ __align__(16) unsigned short Asm[128*40];
  __shared__ __align__(16) unsigned short Bsm[128*40];
  const int tid = threadIdx.x;
  const int lane = tid & 63;
  const int fr = lane & 15, q = lane >> 4;
  if ((int)blockIdx.x < 4096){
    const int bx = blockIdx.x & 15, by = blockIdx.x >> 4;
    const int m0 = by * 128, n0 = bx * 128;
    const int wid = tid >> 6;
    const int wm = (wid >> 1) * 64, wn = (wid & 1) * 64;
    f32x4 acc[4][4];
    #pragma unroll
    for (int i=0;i<4;i++)
      #pragma unroll
      for(int j=0;j<4;j++) acc[i][j] = (f32x4){0.f,0.f,0.f,0.f};
    for (int k0 = 0; k0 < 512; k0 += 32){
      #pragma unroll
      for (int c = 0; c < 2; ++c){
        int ch = tid + c*256;
        int r = ch >> 2, s = (ch & 3) * 8;
        *(uint4*)&Asm[r*40 + s] = *(const uint4*)&A1[(size_t)(m0 + r)*512 + k0 + s];
        *(uint4*)&Bsm[r*40 + s] = *(const uint4*)&B1[(size_t)(n0 + r)*512 + k0 + s];
      }
      __syncthreads();
      bf16x8 af[4], bfv[4];
      #pragma unroll
      for (int i=0;i<4;i++){
        af[i]  = *(const bf16x8*)&Asm[(wm + i*16 + fr)*40 + q*8];
        bfv[i] = *(const bf16x8*)&Bsm[(wn + i*16 + fr)*40 + q*8];
      }
      #pragma unroll
      for (int i=0;i<4;i++)
        #pragma unroll
        for (int j=0;j<4;j++)
          acc[i][j] = __builtin_amdgcn_mfma_f32_16x16x32_bf16(af[i], bfv[j], acc[i][j], 0,0,0);
      __syncthreads();
    }
    #pragma unroll
    for (int i=0;i<4;i++){
      #pragma unroll
      for (int j=0;j<4;j++){
        int n = n0 + wn + j*16 + fr;
        float bv = bias1[n];
        #pragma unroll
        for (int r=0;r<4;r++){
          int m = m0 + wm + i*16 + q*4 + r;
          C1[(size_t)m*2048 + n] = f2bf(acc[i][j][r] + bv);
        }
      }
    }
  } else {
    const int b2 = blockIdx.x - 4096;
    const int bx = b2 & 15, by = b2 >> 4;
    const int m0 = by * 64, n0 = bx * 128;
    const int wid = tid >> 6;
    f32x4 acc[8];
    #pragma unroll
    for (int j=0;j<8;j++) acc[j] = (f32x4){0.f,0.f,0.f,0.f};
    for (int k0 = 0; k0 < 512; k0 += 32){
      {
        int r = tid >> 2, s = (tid & 3) * 8;
        *(uint4*)&Asm[r*40 + s] = *(const uint4*)&A2[(size_t)(m0 + r)*512 + k0 + s];
        #pragma unroll
        for (int c = 0; c < 2; ++c){
          int ch = tid + c*256;
          int rb = ch >> 2, sb = (ch & 3) * 8;
          *(uint4*)&Bsm[rb*40 + sb] = *(const uint4*)&B2[(size_t)(n0 + rb)*512 + k0 + sb];
        }
      }
      __syncthreads();
      bf16x8 af = *(const bf16x8*)&Asm[(wid*16 + fr)*40 + q*8];
      #pragma unroll
      for (int j=0;j<8;j++){
        bf16x8 bv = *(const bf16x8*)&Bsm[(j*16 + fr)*40 + q*8];
        acc[j] = __builtin_amdgcn_mfma_f32_16x16x32_bf16(af, bv, acc[j], 0,0,0);
      }
      __syncthreads();
    }
    #pragma unroll
    for (int j=0;j<8;j++){
      int n = n0 + j*16 + fr;
      float bv = bias2[n];
      #pragma unroll
      for (int r=0;r<4;r++){
        int m = m0 + wid*16 + q*4 + r;
        C2[(size_t)m*2048 + n] = f2bf(acc[j][r] + bv);
      }
    }
  }
}

// ----------------------------- bf16 NT GEMM 64x128 -------------------------
__global__ __launch_bounds__(256) void gemm64_nt(const unsigned short* __restrict__ A, int lda,
    const unsigned short* __restrict__ Bw, int ldb, const float* __restrict__ bias,
    unsigned short* __restrict__ C, int ldc, int M, int N, int K){
  __shared__ __align__(16) unsigned short Asm[64*40];
  __shared__ __align__(16) unsigned short Bsm[128*40];
  const int tid = threadIdx.x;
  const int m0 = blockIdx.y * 64, n0 = blockIdx.x * 128;
  const int lane = tid & 63, wid = tid >> 6;
  const int fr = lane & 15, q = lane >> 4;
  f32x4 acc[8];
  #pragma unroll
  for (int j=0;j<8;j++) acc[j] = (f32x4){0.f,0.f,0.f,0.f};
  for (int k0 = 0; k0 < K; k0 += 32){
    {
      int r = tid >> 2, s = (tid & 3) * 8;
      *(uint4*)&Asm[r*40 + s] = *(const uint4*)&A[(size_t)(m0 + r)*lda + k0 + s];
      #pragma unroll
      for (int c = 0; c < 2; ++c){
        int ch = tid + c*256;
        int rb = ch >> 2, sb = (ch & 3) * 8;
        *(uint4*)&Bsm[rb*40 + sb] = *(const uint4*)&Bw[(size_t)(n0 + rb)*ldb + k0 + sb];
      }
    }
    __syncthreads();
    bf16x8 af = *(const bf16x8*)&Asm[(wid*16 + fr)*40 + q*8];
    #pragma unroll
    for (int j=0;j<8;j++){
      bf16x8 bv = *(const bf16x8*)&Bsm[(j*16 + fr)*40 + q*8];
      acc[j] = __builtin_amdgcn_mfma_f32_16x16x32_bf16(af, bv, acc[j], 0,0,0);
    }
    __syncthreads();
  }
  #pragma unroll
  for (int j=0;j<8;j++){
    int n = n0 + j*16 + fr;
    float bv = bias ? bias[n] : 0.f;
    #pragma unroll
    for (int r=0;r<4;r++){
      int m = m0 + wid*16 + q*4 + r;
      C[(size_t)m*ldc + n] = f2bf(acc[j][r] + bv);
    }
  }
}

// f32-output 64x128 variant (for hWh)
__global__ __launch_bounds__(256) void gemm64_ntf(const unsigned short* __restrict__ A, int lda,
    const unsigned short* __restrict__ Bw, int ldb,
    float* __restrict__ C, int ldc, int M, int N, int K){
  __shared__ __align__(16) unsigned short Asm[64*40];
  __shared__ __align__(16) unsigned short Bsm[128*40];
  const int tid = threadIdx.x;
  const int m0 = blockIdx.y * 64, n0 = blockIdx.x * 128;
  const int lane = tid & 63, wid = tid >> 6;
  const int fr = lane & 15, q = lane >> 4;
  f32x4 acc[8];
  #pragma unroll
  for (int j=0;j<8;j++) acc[j] = (f32x4){0.f,0.f,0.f,0.f};
  for (int k0 = 0; k0 < K; k0 += 32){
    {
      int r = tid >> 2, s = (tid & 3) * 8;
      *(uint4*)&Asm[r*40 + s] = *(const uint4*)&A[(size_t)(m0 + r)*lda + k0 + s];
      #pragma unroll
      for (int c = 0; c < 2; ++c){
        int ch = tid + c*256;
        int rb = ch >> 2, sb = (ch & 3) * 8;
        *(uint4*)&Bsm[rb*40 + sb] = *(const uint4*)&Bw[(size_t)(n0 + rb)*ldb + k0 + sb];
      }
    }
    __syncthreads();
    bf16x8 af = *(const bf16x8*)&Asm[(wid*16 + fr)*40 + q*8];
    #pragma unroll
    for (int j=0;j<8;j++){
      bf16x8 bv = *(const bf16x8*)&Bsm[(j*16 + fr)*40 + q*8];
      acc[j] = __builtin_amdgcn_mfma_f32_16x16x32_bf16(af, bv, acc[j], 0,0,0);
    }
    __syncthreads();
  }
  #pragma unroll
  for (int j=0;j<8;j++){
    int n = n0 + j*16 + fr;
    #pragma unroll
    for (int r=0;r<4;r++){
      int m = m0 + wid*16 + q*4 + r;
      C[(size_t)m*ldc + n] = acc[j][r];
    }
  }
}

// ----------------------------- encoder LSTM (r19 protocol) -----------------
__global__ __launch_bounds__(512) void lstm_enc(
    const unsigned short* __restrict__ xw,    // [nsteps][64][2048] bf16 (bias folded)
    const unsigned short* __restrict__ whh,   // [2048][512] bf16
    float* __restrict__ cbuf, unsigned long long* __restrict__ hbuf,
    unsigned short* __restrict__ encout,      // [64][512][512]
    int t0, int nsteps, unsigned* __restrict__ slots){
  __shared__ __align__(16) unsigned short wlds[128*516];
  __shared__ __align__(16) unsigned short hblds[16*516];
  __shared__ float gbufE[256*9];
  const int tid = threadIdx.x;
  const int g = blockIdx.x & 7, j = blockIdx.x >> 3;
  const int b0 = g*8, u0 = j*64;
  for (int idx = tid; idx < 128*64; idx += 512){
    int n = idx >> 6, ch = idx & 63;
    int R = (n >> 6)*512 + u0 + (n & 63);
    *(uint4*)&wlds[n*516 + ch*8] = *(const uint4*)&whh[(size_t)R*512 + ch*8];
  }
  for (int idx = tid; idx < 1032; idx += 512)
    *(unsigned long long*)&hblds[8*516 + idx*4] = 0ull;
  const int lane = tid & 63, wv = tid >> 6, fr = lane & 15, q = lane >> 4;
  const int m = tid >> 6, j2 = tid & 63;
  bf16x8 breg[16];
  {
    int rl = 128 + wv*16 + fr;
    int R2 = (rl >> 6)*512 + u0 + (rl & 63);
    const unsigned short* wp2 = &whh[(size_t)R2*512 + q*8];
    #pragma unroll
    for (int kk = 0; kk < 16; ++kk)
      breg[kk] = *(const bf16x8*)&wp2[kk*32];
  }
  float cst = cbuf[(b0 + m)*512 + u0 + j2];
  unsigned* myslot = slots + g*16 + j;
  const unsigned* gslots = slots + g*16;
  unsigned short px0, px1, px2, px3;
  {
    size_t xi = ((size_t)t0*64 + b0 + m)*2048 + u0 + j2;
    px0 = xw[xi]; px1 = xw[xi + 512]; px2 = xw[xi + 1024]; px3 = xw[xi + 1536];
  }
  __syncthreads();
  for (int s = 0; s < nsteps; ++s){
    const int t = t0 + s;
    const int rp = t & 1, wp = rp ^ 1;
    {
      const unsigned long long* hq = hbuf + (size_t)rp*8192 + (size_t)b0*128;
      unsigned long long v0 = ldq(&hq[tid]);
      unsigned long long v1 = ldq(&hq[tid + 512]);
      int b2 = tid >> 7, q2 = tid & 127;
      *(unsigned long long*)&hblds[b2*516 + q2*4] = v0;
      *(unsigned long long*)&hblds[(b2 + 4)*516 + q2*4] = v1;
    }
    __syncthreads();
    f32x4 acc = {0.f,0.f,0.f,0.f}, acc2 = {0.f,0.f,0.f,0.f};
    #pragma unroll
    for (int kk = 0; kk < 16; ++kk){
      bf16x8 av = *(const bf16x8*)&hblds[fr*516 + kk*32 + q*8];
      bf16x8 bv = *(const bf16x8*)&wlds[(wv*16 + fr)*516 + kk*32 + q*8];
      acc  = __builtin_amdgcn_mfma_f32_16x16x32_bf16(av, bv,       acc,  0,0,0);
      acc2 = __builtin_amdgcn_mfma_f32_16x16x32_bf16(av, breg[kk], acc2, 0,0,0);
    }
    if (q < 2){
      #pragma unroll
      for (int r = 0; r < 4; ++r){
        gbufE[(wv*16 + fr)*9 + q*4 + r] = acc[r];
        gbufE[(128 + wv*16 + fr)*9 + q*4 + r] = acc2[r];
      }
    }
    __syncthreads();
    unsigned short hv;
    {
      float gi = gbufE[(j2)*9 + m]        + bf2f(px0);
      float gf = gbufE[(64 + j2)*9 + m]   + bf2f(px1);
      float gg = gbufE[(128 + j2)*9 + m]  + bf2f(px2);
      float go = gbufE[(192 + j2)*9 + m]  + bf2f(px3);
      float cc = sigm(gf)*cst + sigm(gi)*tanh2(gg);
      float hh = sigm(go)*tanh2(cc);
      cst = cc;
      hv = f2bf(hh);
      unsigned other = (unsigned)__shfl_xor((int)(unsigned)hv, 1);
      unsigned pair = ((unsigned)hv) | (other << 16);
      unsigned pair2 = (unsigned)__shfl_xor((int)pair, 2);
      if ((j2 & 3) == 0){
        unsigned long long qw = (((unsigned long long)pair2) << 32) | (unsigned long long)pair;
        stq(&hbuf[(size_t)wp*8192 + (size_t)(b0+m)*128 + ((u0 + j2) >> 2)], qw);
      }
    }
    VMWAIT();
    __syncthreads();
    if (tid == 0) stu(myslot, (unsigned)(t + 1));
    encout[((size_t)(b0+m)*512 + t)*512 + u0 + j2] = hv;
    if (s == nsteps - 1) cbuf[(b0+m)*512 + u0 + j2] = cst;
    else {
      size_t xi = ((size_t)(t+1)*64 + b0 + m)*2048 + u0 + j2;
      px0 = xw[xi]; px1 = xw[xi + 512]; px2 = xw[xi + 1024]; px3 = xw[xi + 1536];
    }
    if (tid < 64){
      unsigned target = (unsigned)(t + 1);
      bool mine = (tid < 8);
      const unsigned* sp = gslots + (tid & 7);
      while (true){
        bool ok = true;
        if (mine) ok = (ldu(sp) >= target);
        if (__all(ok)) break;
        __builtin_amdgcn_s_sleep(1);
      }
    }
    __syncthreads();
  }
}

// ----------------------------- decoder LSTM (h-sequence only) --------------
__global__ __launch_bounds__(512) void dec_h(
    const unsigned short* __restrict__ xg,    // [64][48][2048] bf16 (bias folded)
    const unsigned short* __restrict__ whh,   // dec_Whh [2048][512] bf16
    const float* __restrict__ cbuf, unsigned long long* __restrict__ hbuf,
    unsigned short* __restrict__ X,           // [3072][1024]
    unsigned* __restrict__ slots){
  __shared__ __align__(16) unsigned short wlds[128*516];
  __shared__ __align__(16) unsigned short hblds[16*516];
  __shared__ float gbufE[256*9];
  const int tid = threadIdx.x;
  const int g = blockIdx.x & 7, j = blockIdx.x >> 3;
  const int b0 = g*8, u0 = j*64;
  for (int idx = tid; idx < 128*64; idx += 512){
    int n = idx >> 6, ch = idx & 63;
    int R = (n >> 6)*512 + u0 + (n & 63);
    *(uint4*)&wlds[n*516 + ch*8] = *(const uint4*)&whh[(size_t)R*512 + ch*8];
  }
  for (int idx = tid; idx < 1032; idx += 512)
    *(unsigned long long*)&hblds[8*516 + idx*4] = 0ull;
  const int lane = tid & 63, wv = tid >> 6, fr = lane & 15, q = lane >> 4;
  const int m = tid >> 6, j2 = tid & 63;
  bf16x8 breg[16];
  {
    int rl = 128 + wv*16 + fr;
    int R2 = (rl >> 6)*512 + u0 + (rl & 63);
    const unsigned short* wp2 = &whh[(size_t)R2*512 + q*8];
    #pragma unroll
    for (int kk = 0; kk < 16; ++kk)
      breg[kk] = *(const bf16x8*)&wp2[kk*32];
  }
  float cst = cbuf[(b0 + m)*512 + u0 + j2];
  unsigned* myslot = slots + g*16 + j;
  const unsigned* gslots = slots + g*16;
  unsigned short px0, px1, px2, px3;
  {
    size_t xi = ((size_t)(b0 + m)*48)*2048 + u0 + j2;
    px0 = xg[xi]; px1 = xg[xi + 512]; px2 = xg[xi + 1024]; px3 = xg[xi + 1536];
  }
  __syncthreads();
  for (int t = 0; t < 48; ++t){
    const int rp = t & 1, wp = rp ^ 1;
    {
      const unsigned long long* hq = hbuf + (size_t)rp*8192 + (size_t)b0*128;
      unsigned long long v0 = ldq(&hq[tid]);
      unsigned long long v1 = ldq(&hq[tid + 512]);
      int b2 = tid >> 7, q2 = tid & 127;
      *(unsigned long long*)&hblds[b2*516 + q2*4] = v0;
      *(unsigned long long*)&hblds[(b2 + 4)*516 + q2*4] = v1;
    }
    __syncthreads();
    f32x4 acc = {0.f,0.f,0.f,0.f}, acc2 = {0.f,0.f,0.f,0.f};
    #pragma unroll
    for (int kk = 0; kk < 16; ++kk){
      bf16x8 av = *(const bf16x8*)&hblds[fr*516 + kk*32 + q*8];
      bf16x8 bv = *(const bf16x8*)&wlds[(wv*16 + fr)*516 + kk*32 + q*8];
      acc  = __builtin_amdgcn_mfma_f32_16x16x32_bf16(av, bv,       acc,  0,0,0);
      acc2 = __builtin_amdgcn_mfma_f32_16x16x32_bf16(av, breg[kk], acc2, 0,0,0);
    }
    if (q < 2){
      #pragma unroll
      for (int r = 0; r < 4; ++r){
        gbufE[(wv*16 + fr)*9 + q*4 + r] = acc[r];
        gbufE[(128 + wv*16 + fr)*9 + q*4 + r] = acc2[r];
      }
    }
    __syncthreads();
    unsigned short hv;
    {
      float gi = gbufE[(j2)*9 + m]        + bf2f(px0);
      float gf = gbufE[(64 + j2)*9 + m]   + bf2f(px1);
      float gg = gbufE[(128 + j2)*9 + m]  + bf2f(px2);
      float go = gbufE[(192 + j2)*9 + m]  + bf2f(px3);
      float cc = sigm(gf)*cst + sigm(gi)*tanh2(gg);
      float hh = sigm(go)*tanh2(cc);
      cst = cc;
      hv = f2bf(hh);
      unsigned other = (unsigned)__shfl_xor((int)(unsigned)hv, 1);
      unsigned pair = ((unsigned)hv) | (other << 16);
      unsigned pair2 = (unsigned)__shfl_xor((int)pair, 2);
      if ((j2 & 3) == 0){
        unsigned long long qw = (((unsigned long long)pair2) << 32) | (unsigned long long)pair;
        stq(&hbuf[(size_t)wp*8192 + (size_t)(b0+m)*128 + ((u0 + j2) >> 2)], qw);
      }
    }
    VMWAIT();
    __syncthreads();
    if (tid == 0) stu(myslot, (unsigned)(t + 1));
    X[((size_t)t*64 + b0 + m)*1024 + u0 + j2] = hv;
    if (t < 47){
      size_t xi = ((size_t)(b0 + m)*48 + t + 1)*2048 + u0 + j2;
      px0 = xg[xi]; px1 = xg[xi + 512]; px2 = xg[xi + 1024]; px3 = xg[xi + 1536];
    }
    if (tid < 64){
      unsigned target = (unsigned)(t + 1);
      bool mine = (tid < 8);
      const unsigned* sp = gslots + (tid & 7);
      while (true){
        bool ok = true;
        if (mine) ok = (ldu(sp) >= target);
        if (__all(ok)) break;
        __builtin_amdgcn_s_sleep(1);
      }
    }
    __syncthreads();
  }
}

// ----------------------------- attention scores ----------------------------
// grid 2048 = 4 t-chunks x 64 b x 8 lc; each block does 12 t.
__global__ __launch_bounds__(256) void attn_scores(
    const unsigned short* __restrict__ encpart, // [64*512][512]
    const float* __restrict__ hwh,              // [3072][512]
    const float* __restrict__ vvec,
    float* __restrict__ scores){                // [3072][512]
  __shared__ __align__(16) float hwhs[512];
  __shared__ __align__(16) float vm2s[512];
  __shared__ float red[4];
  const int tid = threadIdx.x;
  const int tc = blockIdx.x >> 9;
  const int b = (blockIdx.x >> 3) & 63, lc = blockIdx.x & 7;
  const int l = tid >> 2, kq = tid & 3;
  const int lane = tid & 63, wv = tid >> 6;
  vm2s[tid] = -2.f * vvec[tid];
  vm2s[tid+256] = -2.f * vvec[tid+256];
  __syncthreads();
  float vsumf;
  {
    float x = vm2s[tid] + vm2s[tid+256];
    #pragma unroll
    for (int off=32; off; off>>=1) x += __shfl_xor(x, off);
    if (lane == 0) red[wv] = x;
    __syncthreads();
    vsumf = -0.5f * (red[0]+red[1]+red[2]+red[3]);
  }
  bf16x8 epr[16];
  {
    const unsigned short* ep = encpart + ((size_t)(b*512 + lc*64 + l))*512 + kq*128;
    #pragma unroll
    for (int i = 0; i < 16; ++i) epr[i] = *(const bf16x8*)&ep[i*8];
  }
  const float C = 2.88539008f;
  for (int t = tc*12; t < tc*12 + 12; ++t){
    __syncthreads();
    hwhs[tid]     = C * hwh[((size_t)t*64 + b)*512 + tid];
    hwhs[tid+256] = C * hwh[((size_t)t*64 + b)*512 + tid + 256];
    __syncthreads();
    float sacc = 0.f;
    #pragma unroll
    for (int kk = 0; kk < 16; ++kk){
      float4 h0 = *(const float4*)&hwhs[kq*128 + kk*8];
      float4 h1 = *(const float4*)&hwhs[kq*128 + kk*8 + 4];
      float4 v0 = *(const float4*)&vm2s[kq*128 + kk*8];
      float4 v1 = *(const float4*)&vm2s[kq*128 + kk*8 + 4];
      const unsigned short* e = (const unsigned short*)&epr[kk];
      float hw[8] = {h0.x,h0.y,h0.z,h0.w,h1.x,h1.y,h1.z,h1.w};
      float vv[8] = {v0.x,v0.y,v0.z,v0.w,v1.x,v1.y,v1.z,v1.w};
      #pragma unroll
      for (int ee = 0; ee < 8; ++ee){
        float a = fmaf(bf2f(e[ee]), C, hw[ee]);
        sacc = fmaf(vv[ee], __builtin_amdgcn_rcpf(1.f + __builtin_amdgcn_exp2f(a)), sacc);
      }
    }
    sacc += __shfl_xor(sacc, 1);
    sacc += __shfl_xor(sacc, 2);
    if (kq == 0) scores[((size_t)t*64 + b)*512 + lc*64 + l] = vsumf + sacc;
  }
}

// ------------------- ctx with fused softmax (2 blocks/batch) ---------------
// 128 blocks = 64 b x 2 halves (24 t each). encout read once per half:
// 64MB total (was 128MB at 4 blocks/b). Softmax arithmetic unchanged.
__global__ __launch_bounds__(256) void ctx_k(
    const float* __restrict__ scores,           // [3072][512]
    const unsigned short* __restrict__ encout,  // [64*512][512]
    unsigned short* __restrict__ X){
  __shared__ unsigned short awt[512*24];   // [l][tt]
  __shared__ float red[4];
  const int tid = threadIdx.x;
  const int b = blockIdx.x >> 1, t0 = (blockIdx.x & 1)*24;
  const int lane = tid & 63, wv = tid >> 6;
  for (int tt = 0; tt < 24; ++tt){
    size_t row = (size_t)(t0 + tt)*64 + b;
    float v0 = scores[row*512 + tid];
    float v1 = scores[row*512 + tid + 256];
    float mx = fmaxf(v0, v1);
    #pragma unroll
    for (int off=32; off; off>>=1) mx = fmaxf(mx, __shfl_xor(mx, off));
    if (lane == 0) red[wv] = mx;
    __syncthreads();
    mx = fmaxf(fmaxf(red[0],red[1]), fmaxf(red[2],red[3]));
    __syncthreads();
    float e0 = __expf(v0 - mx), e1 = __expf(v1 - mx);
    float ps = e0 + e1;
    #pragma unroll
    for (int off=32; off; off>>=1) ps += __shfl_xor(ps, off);
    if (lane == 0) red[wv] = ps;
    __syncthreads();
    float inv = 1.f / (red[0]+red[1]+red[2]+red[3]);
    awt[tid*24 + tt]         = f2bf(e0 * inv);
    awt[(tid + 256)*24 + tt] = f2bf(e1 * inv);
    __syncthreads();
  }
  float a0[24], a1[24];
  #pragma unroll
  for (int j = 0; j < 24; ++j){ a0[j] = 0.f; a1[j] = 0.f; }
  const unsigned* eo = (const unsigned*)(encout + (size_t)b*512*512) + tid;
  for (int ll = 0; ll < 512; ++ll){
    unsigned ee = eo[(size_t)ll*256];
    float e0 = __uint_as_float((ee & 0xffffu) << 16);
    float e1 = __uint_as_float(ee & 0xffff0000u);
    const unsigned* wp2 = (const unsigned*)&awt[ll*24];
    float w[24];
    #pragma unroll
    for (int z = 0; z < 12; ++z){
      unsigned wu = wp2[z];
      w[2*z]   = bf2f((unsigned short)(wu & 0xffffu));
      w[2*z+1] = bf2f((unsigned short)(wu >> 16));
    }
    #pragma unroll
    for (int j = 0; j < 24; ++j){
      a0[j] = fmaf(w[j], e0, a0[j]);
      a1[j] = fmaf(w[j], e1, a1[j]);
    }
  }
  #pragma unroll
  for (int j = 0; j < 24; ++j){
    size_t r = (size_t)(t0+j)*64 + b;
    unsigned pk = ((unsigned)f2bf(a0[j])) | (((unsigned)f2bf(a1[j])) << 16);
    *(unsigned*)&X[r*1024 + 512 + 2*tid] = pk;
  }
}

// ----------------------------- projection ----------------------------------
__global__ void proj_k(const unsigned short* __restrict__ outs,
                       const float* __restrict__ pw, const float* __restrict__ pb,
                       float* __restrict__ out){
  int gid = blockIdx.x*256 + threadIdx.x;
  if (gid >= 64*48*7) return;
  int r = gid / 7, oc = gid % 7;
  int b = r & 63, t = r >> 6;
  const unsigned short* orow = outs + (size_t)r*512;
  const float* wrow = pw + oc*512;
  float s = pb[oc];
  for (int k = 0; k < 512; k += 8){
    bf16x8 o8 = *(const bf16x8*)&orow[k];
    #pragma unroll
    for (int e=0;e<8;e++) s += bf2f(((unsigned short*)&o8)[e]) * wrow[k+e];
  }
  out[((size_t)b*48 + t)*7 + oc] = s;
}

// ----------------------------- launch --------------------------------------
extern "C" void kernel_launch(void* const* d_in, const int* in_sizes, int n_in,
                              void* d_out, int out_size, void* d_ws, size_t ws_size,
                              hipStream_t stream){
  (void)in_sizes; (void)n_in; (void)out_size; (void)ws_size;
  const float* x_enc   = (const float*)d_in[0];
  const float* x_dec   = (const float*)d_in[1];
  const float* w_emb_e = (const float*)d_in[2];
  const float* w_emb_d = (const float*)d_in[3];
  const float* enc_Wih = (const float*)d_in[4];
  const float* enc_Whh = (const float*)d_in[5];
  const float* enc_b   = (const float*)d_in[6];
  const float* dec_Wih = (const float*)d_in[7];
  const float* dec_Whh = (const float*)d_in[8];
  const float* dec_b   = (const float*)d_in[9];
  const float* attn_W  = (const float*)d_in[10];
  const float* attn_b  = (const float*)d_in[11];
  const float* vvec    = (const float*)d_in[12];
  const float* fc_W    = (const float*)d_in[13];
  const float* fc_b    = (const float*)d_in[14];
  const float* proj_W  = (const float*)d_in[15];
  const float* proj_b  = (const float*)d_in[16];
  float* out = (float*)d_out;

  char* ws = (char*)d_ws;
  size_t off = 0;
  auto alloc = [&](size_t bytes)->char*{
    char* p = ws + off;
    off = (off + bytes + 255) & ~(size_t)255;
    return p;
  };
  unsigned short* encxw  = (unsigned short*)alloc(512ull*64*2048*2); // all steps
  unsigned short* encin  = (unsigned short*)alloc(512ull*64*512*2);  // embed; reused as enc_part
  unsigned short* encout = (unsigned short*)alloc(64ull*512*512*2);
  unsigned short* xs     = (unsigned short*)alloc(64ull*48*512*2);
  unsigned short* xg     = (unsigned short*)alloc(64ull*48*2048*2);
  unsigned short* Xb     = (unsigned short*)alloc(3072ull*1024*2);
  float* hwh    = (float*)alloc(3072ull*512*4);
  float* scores = (float*)alloc(3072ull*512*4);
  unsigned short* outsb  = (unsigned short*)alloc(3072ull*512*2);
  unsigned short* wih_e  = (unsigned short*)alloc(2048ull*512*2);
  unsigned short* whh_e  = (unsigned short*)alloc(2048ull*512*2);
  unsigned short* wih_d  = (unsigned short*)alloc(2048ull*512*2);
  unsigned short* whh_d  = (unsigned short*)alloc(2048ull*512*2);
  unsigned short* whq    = (unsigned short*)alloc(512ull*512*2);
  unsigned short* weq    = (unsigned short*)alloc(512ull*512*2);
  unsigned short* fcw    = (unsigned short*)alloc(512ull*1024*2);
  unsigned long long* hbuf = (unsigned long long*)alloc(2ull*64*128*8);
  float* cbuf   = (float*)alloc(64ull*512*4);
  unsigned* eslots = (unsigned*)alloc(4*64*4);
  unsigned* dslots = (unsigned*)alloc(4*64*4);

  hipMemsetAsync(hbuf, 0, 2ull*64*128*8, stream);
  hipMemsetAsync(cbuf, 0, 64ull*512*4, stream);
  hipMemsetAsync(eslots, 0, 4*64*4, stream);
  hipMemsetAsync(dslots, 0, 4*64*4, stream);

  // merged prep: embeds + all weight casts (10304 blocks x 512)
  prep_k<<<10304, 512, 0, stream>>>(x_enc, x_dec, w_emb_e, w_emb_d, encin, xs,
                                    enc_Wih, enc_Whh, dec_Wih, dec_Whh, fc_W, attn_W,
                                    wih_e, whh_e, wih_d, whh_d, fcw, whq, weq);

  // merged staging GEMM (encxw) + xg gemm64 (4864 blocks)
  gemm_pair_k<<<4864, 256, 0, stream>>>(encin, wih_e, enc_b, encxw,
                                        xs, wih_d, dec_b, xg);

  // ONE persistent lstm launch, 512 steps (8 groups x 8 unit-blocks)
  lstm_enc<<<64, 512, 0, stream>>>(encxw, whh_e, cbuf, hbuf, encout, 0, 512, eslots);

  // enc_part = encout @ We^T + attn_b  (reuses encin buffer)
  gemm_nt<<<dim3(4, 256), 256, 0, stream>>>(encout, 512, weq, 512, attn_b, encin, 512, 32768, 512, 512);

  // decoder LSTM h-sequence -> X[:, :512]
  dec_h<<<64, 512, 0, stream>>>(xg, whh_d, cbuf, hbuf, Xb, dslots);

  // hWh = h @ Wh^T  (f32)  (64-row tiles, 192 blocks)
  gemm64_ntf<<<dim3(4, 48), 256, 0, stream>>>(Xb, 1024, whq, 512, hwh, 512, 3072, 512, 512);

  // scores (4x t-parallel), then ctx with fused softmax (2 blocks/batch)
  attn_scores<<<2048, 256, 0, stream>>>(encin /*enc_part*/, hwh, vvec, scores);
  ctx_k<<<128, 256, 0, stream>>>(scores, encout, Xb);

  // fc: [h|ctx] @ fc_W^T + fc_b  (64-row tiles, 192 blocks)
  gemm64_nt<<<dim3(4, 48), 256, 0, stream>>>(Xb, 1024, fcw, 1024, fc_b, outsb, 512, 3072, 512, 1024);

  proj_k<<<84, 256, 0, stream>>>(outsb, proj_W, proj_b, out);
}

// Round 12
// 2211.729 us; speedup vs baseline: 1.0312x; 1.0312x over previous
//
#include <hip/hip_runtime.h>
#include <hip/hip_bf16.h>

// ---------------------------------------------------------------------------
// conv1d embed -> LSTM encoder (512 steps, B=64, H=512) -> decoder (decoupled
// h-recurrence + batched attention) -> projection.
// r28 = r26 exact revert (verified 2222us, session best). r27's ctx 24-t
// variant regressed: 48 f32 accumulators + 24.6KB awt cost more in VGPR/
// occupancy than the halved encout traffic saved (reads were L2/L3-served
// at 1.4% HBM). Session-final configuration:
//  - r19 LSTM flag protocol (best of 5 measured exchange designs: flags
//    1452 < tagged-8B 1622 < tagged-4B 1753; XCD-local failed 3x; release
//    fences 3x worse). Latency floor: 512 serial steps x 4 agent-scope
//    coherence legs.
//  - merged prep (embeds + casts), merged staging+xg GEMM, gemm64 for
//    thin-M matmuls, 4x t-split attn_scores, softmax fused into ctx.
//  - NOT merged: dec_h + enc_part GEMM (r5/r9/r15: background traffic
//    inflates the latency-bound recurrence ~2.5x).
// Math order unchanged everywhere -> same absmax.
// ---------------------------------------------------------------------------

typedef short bf16x8 __attribute__((ext_vector_type(8)));
typedef float f32x4 __attribute__((ext_vector_type(4)));

static __device__ __forceinline__ float bf2f(unsigned short u){
  return __uint_as_float(((unsigned)u) << 16);
}
static __device__ __forceinline__ unsigned short f2bf(float f){
  unsigned x = __float_as_uint(f);
  return (unsigned short)((x + 0x7fffu + ((x >> 16) & 1u)) >> 16);   // RNE
}
static __device__ __forceinline__ float sigm(float x){
  return __builtin_amdgcn_rcpf(1.f + __builtin_amdgcn_exp2f(-1.44269504f*x));
}
static __device__ __forceinline__ float tanh2(float x){
  return 1.f - 2.f*__builtin_amdgcn_rcpf(1.f + __builtin_amdgcn_exp2f(2.88539008f*x));
}

static __device__ __forceinline__ unsigned ldu(const unsigned* p){
  return __hip_atomic_load(p, __ATOMIC_RELAXED, __HIP_MEMORY_SCOPE_AGENT);
}
static __device__ __forceinline__ void stu(unsigned* p, unsigned v){
  __hip_atomic_store(p, v, __ATOMIC_RELAXED, __HIP_MEMORY_SCOPE_AGENT);
}
static __device__ __forceinline__ unsigned long long ldq(const unsigned long long* p){
  return __hip_atomic_load(p, __ATOMIC_RELAXED, __HIP_MEMORY_SCOPE_AGENT);
}
static __device__ __forceinline__ void stq(unsigned long long* p, unsigned long long v){
  __hip_atomic_store(p, v, __ATOMIC_RELAXED, __HIP_MEMORY_SCOPE_AGENT);
}
#define VMWAIT() __asm__ __volatile__("s_waitcnt vmcnt(0)" ::: "memory")

// ----------------------------- merged prep kernel --------------------------
// blocks 0..511   : embed encoder (64 b x 8 chunks)
// blocks 512..575 : embed decoder (64 b x 1 chunk)
// blocks 576..    : casts (4x 1048576 + 524288 + 262144 = 4980736 elems,
//                   512 threads/block -> 9728 blocks; total 10304 blocks)
__global__ __launch_bounds__(512) void prep_k(
    const float* __restrict__ x_enc, const float* __restrict__ x_dec,
    const float* __restrict__ w_emb_e, const float* __restrict__ w_emb_d,
    unsigned short* __restrict__ encin, unsigned short* __restrict__ xs,
    const float* __restrict__ a0, const float* __restrict__ a1,
    const float* __restrict__ a2, const float* __restrict__ a3,
    const float* __restrict__ a4, const float* __restrict__ aw,
    unsigned short* __restrict__ d0, unsigned short* __restrict__ d1,
    unsigned short* __restrict__ d2, unsigned short* __restrict__ d3,
    unsigned short* __restrict__ d4,
    unsigned short* __restrict__ wh, unsigned short* __restrict__ we){
  __shared__ float wl[512*21];
  __shared__ float xl[66*7];
  const int bid = blockIdx.x, tid = threadIdx.x;
  if (bid < 576){
    const float* x; const float* wconv; unsigned short* outp;
    int Lx, l0, lcount, mode, nch, rel;
    if (bid < 512){ x = x_enc; wconv = w_emb_e; outp = encin;
                    Lx = 512; l0 = 0; lcount = 512; mode = 0; nch = 8; rel = bid; }
    else          { x = x_dec; wconv = w_emb_d; outp = xs;
                    Lx = 144; l0 = 48; lcount = 48; mode = 1; nch = 1; rel = bid - 512; }
    const int Bsz = 64;
    int b = rel / nch, ci = rel % nch;
    for (int i = tid; i < 512*21; i += 512) wl[i] = wconv[i];
    int lstart = l0 + ci*64;
    int cnt = l0 + lcount - lstart; if (cnt > 64) cnt = 64;
    int nwin = (cnt + 2) * 7;
    for (int i = tid; i < nwin; i += 512){
      int wr = i / 7, c = i % 7;
      int gl = lstart - 1 + wr;
      gl = (gl + Lx) % Lx;
      xl[i] = x[((size_t)b*Lx + gl)*7 + c];
    }
    __syncthreads();
    int o = tid;
    float fe = (float)(o & ~1);
    float div = __expf(fe * -0.0179889461f);
    const float* wrow = &wl[o*21];
    for (int li = 0; li < cnt; ++li){
      int l = lstart + li;
      float acc = 0.f;
      #pragma unroll
      for (int c = 0; c < 7; ++c)
        #pragma unroll
        for (int kk = 0; kk < 3; ++kk)
          acc += xl[(li + kk)*7 + c] * wrow[c*3 + kk];
      float arg = (float)l * div;
      acc += (o & 1) ? cosf(arg) : sinf(arg);
      size_t oi = mode ? (((size_t)b*lcount + (l - l0))*512 + o)
                       : (((size_t)l*Bsz + b)*512 + o);
      outp[oi] = f2bf(acc);
    }
    return;
  }
  int i = (bid - 576)*512 + tid;
  if (i < 1048576){ d0[i] = f2bf(a0[i]); return; }
  i -= 1048576;
  if (i < 1048576){ d1[i] = f2bf(a1[i]); return; }
  i -= 1048576;
  if (i < 1048576){ d2[i] = f2bf(a2[i]); return; }
  i -= 1048576;
  if (i < 1048576){ d3[i] = f2bf(a3[i]); return; }
  i -= 1048576;
  if (i < 524288){ d4[i] = f2bf(a4[i]); return; }
  i -= 524288;
  if (i < 262144){
    int nrow = i >> 9, k = i & 511;
    wh[i] = f2bf(aw[(size_t)nrow*1024 + k]);
    we[i] = f2bf(aw[(size_t)nrow*1024 + 512 + k]);
  }
}

// ----------------------------- bf16 NT GEMM 128x128 ------------------------
__global__ __launch_bounds__(256) void gemm_nt(const unsigned short* __restrict__ A, int lda,
    const unsigned short* __restrict__ Bw, int ldb, const float* __restrict__ bias,
    unsigned short* __restrict__ C, int ldc, int M, int N, int K){
  __shared__ __align__(16) unsigned short Asm[128*40];
  __shared__ __align__(16) unsigned short Bsm[128*40];
  const int tid = threadIdx.x;
  const int m0 = blockIdx.y * 128, n0 = blockIdx.x * 128;
  const int lane = tid & 63;
  const int wid = tid >> 6;
  const int wm = (wid >> 1) * 64, wn = (wid & 1) * 64;
  const int fr = lane & 15, q = lane >> 4;
  f32x4 acc[4][4];
  #pragma unroll
  for (int i=0;i<4;i++)
    #pragma unroll
    for(int j=0;j<4;j++) acc[i][j] = (f32x4){0.f,0.f,0.f,0.f};
  for (int k0 = 0; k0 < K; k0 += 32){
    #pragma unroll
    for (int c = 0; c < 2; ++c){
      int ch = tid + c*256;
      int r = ch >> 2, s = (ch & 3) * 8;
      *(uint4*)&Asm[r*40 + s] = *(const uint4*)&A[(size_t)(m0 + r)*lda + k0 + s];
      *(uint4*)&Bsm[r*40 + s] = *(const uint4*)&Bw[(size_t)(n0 + r)*ldb + k0 + s];
    }
    __syncthreads();
    bf16x8 af[4], bfv[4];
    #pragma unroll
    for (int i=0;i<4;i++){
      af[i]  = *(const bf16x8*)&Asm[(wm + i*16 + fr)*40 + q*8];
      bfv[i] = *(const bf16x8*)&Bsm[(wn + i*16 + fr)*40 + q*8];
    }
    #pragma unroll
    for (int i=0;i<4;i++)
      #pragma unroll
      for (int j=0;j<4;j++)
        acc[i][j] = __builtin_amdgcn_mfma_f32_16x16x32_bf16(af[i], bfv[j], acc[i][j], 0,0,0);
    __syncthreads();
  }
  #pragma unroll
  for (int i=0;i<4;i++){
    #pragma unroll
    for (int j=0;j<4;j++){
      int n = n0 + wn + j*16 + fr;
      float bv = bias ? bias[n] : 0.f;
      #pragma unroll
      for (int r=0;r<4;r++){
        int m = m0 + wm + i*16 + q*4 + r;
        C[(size_t)m*ldc + n] = f2bf(acc[i][j][r] + bv);
      }
    }
  }
}

// ------------------- merged staging GEMM + xg gemm64 -----------------------
// blocks 0..4095   : staging  encxw = encin @ wih_e^T + enc_b  [32768][2048]
// blocks 4096..4863: xg       xg    = xs    @ wih_d^T + dec_b  [3072][2048]
__global__ __launch_bounds__(256) void gemm_pair_k(
    const unsigned short* __restrict__ A1, const unsigned short* __restrict__ B1,
    const float* __restrict__ bias1, unsigned short* __restrict__ C1,
    const unsigned short* __restrict__ A2, const unsigned short* __restrict__ B2,
    const float* __restrict__ bias2, unsigned short* __restrict__ C2){
  __shared__ __align__(16) unsigned short Asm[128*40];
  __shared__ __align__(16) unsigned short Bsm[128*40];
  const int tid = threadIdx.x;
  const int lane = tid & 63;
  const int fr = lane & 15, q = lane >> 4;
  if ((int)blockIdx.x < 4096){
    const int bx = blockIdx.x & 15, by = blockIdx.x >> 4;
    const int m0 = by * 128, n0 = bx * 128;
    const int wid = tid >> 6;
    const int wm = (wid >> 1) * 64, wn = (wid & 1) * 64;
    f32x4 acc[4][4];
    #pragma unroll
    for (int i=0;i<4;i++)
      #pragma unroll
      for(int j=0;j<4;j++) acc[i][j] = (f32x4){0.f,0.f,0.f,0.f};
    for (int k0 = 0; k0 < 512; k0 += 32){
      #pragma unroll
      for (int c = 0; c < 2; ++c){
        int ch = tid + c*256;
        int r = ch >> 2, s = (ch & 3) * 8;
        *(uint4*)&Asm[r*40 + s] = *(const uint4*)&A1[(size_t)(m0 + r)*512 + k0 + s];
        *(uint4*)&Bsm[r*40 + s] = *(const uint4*)&B1[(size_t)(n0 + r)*512 + k0 + s];
      }
      __syncthreads();
      bf16x8 af[4], bfv[4];
      #pragma unroll
      for (int i=0;i<4;i++){
        af[i]  = *(const bf16x8*)&Asm[(wm + i*16 + fr)*40 + q*8];
        bfv[i] = *(const bf16x8*)&Bsm[(wn + i*16 + fr)*40 + q*8];
      }
      #pragma unroll
      for (int i=0;i<4;i++)
        #pragma unroll
        for (int j=0;j<4;j++)
          acc[i][j] = __builtin_amdgcn_mfma_f32_16x16x32_bf16(af[i], bfv[j], acc[i][j], 0,0,0);
      __syncthreads();
    }
    #pragma unroll
    for (int i=0;i<4;i++){
      #pragma unroll
      for (int j=0;j<4;j++){
        int n = n0 + wn + j*16 + fr;
        float bv = bias1[n];
        #pragma unroll
        for (int r=0;r<4;r++){
          int m = m0 + wm + i*16 + q*4 + r;
          C1[(size_t)m*2048 + n] = f2bf(acc[i][j][r] + bv);
        }
      }
    }
  } else {
    const int b2 = blockIdx.x - 4096;
    const int bx = b2 & 15, by = b2 >> 4;
    const int m0 = by * 64, n0 = bx * 128;
    const int wid = tid >> 6;
    f32x4 acc[8];
    #pragma unroll
    for (int j=0;j<8;j++) acc[j] = (f32x4){0.f,0.f,0.f,0.f};
    for (int k0 = 0; k0 < 512; k0 += 32){
      {
        int r = tid >> 2, s = (tid & 3) * 8;
        *(uint4*)&Asm[r*40 + s] = *(const uint4*)&A2[(size_t)(m0 + r)*512 + k0 + s];
        #pragma unroll
        for (int c = 0; c < 2; ++c){
          int ch = tid + c*256;
          int rb = ch >> 2, sb = (ch & 3) * 8;
          *(uint4*)&Bsm[rb*40 + sb] = *(const uint4*)&B2[(size_t)(n0 + rb)*512 + k0 + sb];
        }
      }
      __syncthreads();
      bf16x8 af = *(const bf16x8*)&Asm[(wid*16 + fr)*40 + q*8];
      #pragma unroll
      for (int j=0;j<8;j++){
        bf16x8 bv = *(const bf16x8*)&Bsm[(j*16 + fr)*40 + q*8];
        acc[j] = __builtin_amdgcn_mfma_f32_16x16x32_bf16(af, bv, acc[j], 0,0,0);
      }
      __syncthreads();
    }
    #pragma unroll
    for (int j=0;j<8;j++){
      int n = n0 + j*16 + fr;
      float bv = bias2[n];
      #pragma unroll
      for (int r=0;r<4;r++){
        int m = m0 + wid*16 + q*4 + r;
        C2[(size_t)m*2048 + n] = f2bf(acc[j][r] + bv);
      }
    }
  }
}

// ----------------------------- bf16 NT GEMM 64x128 -------------------------
__global__ __launch_bounds__(256) void gemm64_nt(const unsigned short* __restrict__ A, int lda,
    const unsigned short* __restrict__ Bw, int ldb, const float* __restrict__ bias,
    unsigned short* __restrict__ C, int ldc, int M, int N, int K){
  __shared__ __align__(16) unsigned short Asm[64*40];
  __shared__ __align__(16) unsigned short Bsm[128*40];
  const int tid = threadIdx.x;
  const int m0 = blockIdx.y * 64, n0 = blockIdx.x * 128;
  const int lane = tid & 63, wid = tid >> 6;
  const int fr = lane & 15, q = lane >> 4;
  f32x4 acc[8];
  #pragma unroll
  for (int j=0;j<8;j++) acc[j] = (f32x4){0.f,0.f,0.f,0.f};
  for (int k0 = 0; k0 < K; k0 += 32){
    {
      int r = tid >> 2, s = (tid & 3) * 8;
      *(uint4*)&Asm[r*40 + s] = *(const uint4*)&A[(size_t)(m0 + r)*lda + k0 + s];
      #pragma unroll
      for (int c = 0; c < 2; ++c){
        int ch = tid + c*256;
        int rb = ch >> 2, sb = (ch & 3) * 8;
        *(uint4*)&Bsm[rb*40 + sb] = *(const uint4*)&Bw[(size_t)(n0 + rb)*ldb + k0 + sb];
      }
    }
    __syncthreads();
    bf16x8 af = *(const bf16x8*)&Asm[(wid*16 + fr)*40 + q*8];
    #pragma unroll
    for (int j=0;j<8;j++){
      bf16x8 bv = *(const bf16x8*)&Bsm[(j*16 + fr)*40 + q*8];
      acc[j] = __builtin_amdgcn_mfma_f32_16x16x32_bf16(af, bv, acc[j], 0,0,0);
    }
    __syncthreads();
  }
  #pragma unroll
  for (int j=0;j<8;j++){
    int n = n0 + j*16 + fr;
    float bv = bias ? bias[n] : 0.f;
    #pragma unroll
    for (int r=0;r<4;r++){
      int m = m0 + wid*16 + q*4 + r;
      C[(size_t)m*ldc + n] = f2bf(acc[j][r] + bv);
    }
  }
}

// f32-output 64x128 variant (for hWh)
__global__ __launch_bounds__(256) void gemm64_ntf(const unsigned short* __restrict__ A, int lda,
    const unsigned short* __restrict__ Bw, int ldb,
    float* __restrict__ C, int ldc, int M, int N, int K){
  __shared__ __align__(16) unsigned short Asm[64*40];
  __shared__ __align__(16) unsigned short Bsm[128*40];
  const int tid = threadIdx.x;
  const int m0 = blockIdx.y * 64, n0 = blockIdx.x * 128;
  const int lane = tid & 63, wid = tid >> 6;
  const int fr = lane & 15, q = lane >> 4;
  f32x4 acc[8];
  #pragma unroll
  for (int j=0;j<8;j++) acc[j] = (f32x4){0.f,0.f,0.f,0.f};
  for (int k0 = 0; k0 < K; k0 += 32){
    {
      int r = tid >> 2, s = (tid & 3) * 8;
      *(uint4*)&Asm[r*40 + s] = *(const uint4*)&A[(size_t)(m0 + r)*lda + k0 + s];
      #pragma unroll
      for (int c = 0; c < 2; ++c){
        int ch = tid + c*256;
        int rb = ch >> 2, sb = (ch & 3) * 8;
        *(uint4*)&Bsm[rb*40 + sb] = *(const uint4*)&Bw[(size_t)(n0 + rb)*ldb + k0 + sb];
      }
    }
    __syncthreads();
    bf16x8 af = *(const bf16x8*)&Asm[(wid*16 + fr)*40 + q*8];
    #pragma unroll
    for (int j=0;j<8;j++){
      bf16x8 bv = *(const bf16x8*)&Bsm[(j*16 + fr)*40 + q*8];
      acc[j] = __builtin_amdgcn_mfma_f32_16x16x32_bf16(af, bv, acc[j], 0,0,0);
    }
    __syncthreads();
  }
  #pragma unroll
  for (int j=0;j<8;j++){
    int n = n0 + j*16 + fr;
    #pragma unroll
    for (int r=0;r<4;r++){
      int m = m0 + wid*16 + q*4 + r;
      C[(size_t)m*ldc + n] = acc[j][r];
    }
  }
}

// ----------------------------- encoder LSTM (r19 protocol) -----------------
__global__ __launch_bounds__(512) void lstm_enc(
    const unsigned short* __restrict__ xw,    // [nsteps][64][2048] bf16 (bias folded)
    const unsigned short* __restrict__ whh,   // [2048][512] bf16
    float* __restrict__ cbuf, unsigned long long* __restrict__ hbuf,
    unsigned short* __restrict__ encout,      // [64][512][512]
    int t0, int nsteps, unsigned* __restrict__ slots){
  __shared__ __align__(16) unsigned short wlds[128*516];
  __shared__ __align__(16) unsigned short hblds[16*516];
  __shared__ float gbufE[256*9];
  const int tid = threadIdx.x;
  const int g = blockIdx.x & 7, j = blockIdx.x >> 3;
  const int b0 = g*8, u0 = j*64;
  for (int idx = tid; idx < 128*64; idx += 512){
    int n = idx >> 6, ch = idx & 63;
    int R = (n >> 6)*512 + u0 + (n & 63);
    *(uint4*)&wlds[n*516 + ch*8] = *(const uint4*)&whh[(size_t)R*512 + ch*8];
  }
  for (int idx = tid; idx < 1032; idx += 512)
    *(unsigned long long*)&hblds[8*516 + idx*4] = 0ull;
  const int lane = tid & 63, wv = tid >> 6, fr = lane & 15, q = lane >> 4;
  const int m = tid >> 6, j2 = tid & 63;
  bf16x8 breg[16];
  {
    int rl = 128 + wv*16 + fr;
    int R2 = (rl >> 6)*512 + u0 + (rl & 63);
    const unsigned short* wp2 = &whh[(size_t)R2*512 + q*8];
    #pragma unroll
    for (int kk = 0; kk < 16; ++kk)
      breg[kk] = *(const bf16x8*)&wp2[kk*32];
  }
  float cst = cbuf[(b0 + m)*512 + u0 + j2];
  unsigned* myslot = slots + g*16 + j;
  const unsigned* gslots = slots + g*16;
  unsigned short px0, px1, px2, px3;
  {
    size_t xi = ((size_t)t0*64 + b0 + m)*2048 + u0 + j2;
    px0 = xw[xi]; px1 = xw[xi + 512]; px2 = xw[xi + 1024]; px3 = xw[xi + 1536];
  }
  __syncthreads();
  for (int s = 0; s < nsteps; ++s){
    const int t = t0 + s;
    const int rp = t & 1, wp = rp ^ 1;
    {
      const unsigned long long* hq = hbuf + (size_t)rp*8192 + (size_t)b0*128;
      unsigned long long v0 = ldq(&hq[tid]);
      unsigned long long v1 = ldq(&hq[tid + 512]);
      int b2 = tid >> 7, q2 = tid & 127;
      *(unsigned long long*)&hblds[b2*516 + q2*4] = v0;
      *(unsigned long long*)&hblds[(b2 + 4)*516 + q2*4] = v1;
    }
    __syncthreads();
    f32x4 acc = {0.f,0.f,0.f,0.f}, acc2 = {0.f,0.f,0.f,0.f};
    #pragma unroll
    for (int kk = 0; kk < 16; ++kk){
      bf16x8 av = *(const bf16x8*)&hblds[fr*516 + kk*32 + q*8];
      bf16x8 bv = *(const bf16x8*)&wlds[(wv*16 + fr)*516 + kk*32 + q*8];
      acc  = __builtin_amdgcn_mfma_f32_16x16x32_bf16(av, bv,       acc,  0,0,0);
      acc2 = __builtin_amdgcn_mfma_f32_16x16x32_bf16(av, breg[kk], acc2, 0,0,0);
    }
    if (q < 2){
      #pragma unroll
      for (int r = 0; r < 4; ++r){
        gbufE[(wv*16 + fr)*9 + q*4 + r] = acc[r];
        gbufE[(128 + wv*16 + fr)*9 + q*4 + r] = acc2[r];
      }
    }
    __syncthreads();
    unsigned short hv;
    {
      float gi = gbufE[(j2)*9 + m]        + bf2f(px0);
      float gf = gbufE[(64 + j2)*9 + m]   + bf2f(px1);
      float gg = gbufE[(128 + j2)*9 + m]  + bf2f(px2);
      float go = gbufE[(192 + j2)*9 + m]  + bf2f(px3);
      float cc = sigm(gf)*cst + sigm(gi)*tanh2(gg);
      float hh = sigm(go)*tanh2(cc);
      cst = cc;
      hv = f2bf(hh);
      unsigned other = (unsigned)__shfl_xor((int)(unsigned)hv, 1);
      unsigned pair = ((unsigned)hv) | (other << 16);
      unsigned pair2 = (unsigned)__shfl_xor((int)pair, 2);
      if ((j2 & 3) == 0){
        unsigned long long qw = (((unsigned long long)pair2) << 32) | (unsigned long long)pair;
        stq(&hbuf[(size_t)wp*8192 + (size_t)(b0+m)*128 + ((u0 + j2) >> 2)], qw);
      }
    }
    VMWAIT();
    __syncthreads();
    if (tid == 0) stu(myslot, (unsigned)(t + 1));
    encout[((size_t)(b0+m)*512 + t)*512 + u0 + j2] = hv;
    if (s == nsteps - 1) cbuf[(b0+m)*512 + u0 + j2] = cst;
    else {
      size_t xi = ((size_t)(t+1)*64 + b0 + m)*2048 + u0 + j2;
      px0 = xw[xi]; px1 = xw[xi + 512]; px2 = xw[xi + 1024]; px3 = xw[xi + 1536];
    }
    if (tid < 64){
      unsigned target = (unsigned)(t + 1);
      bool mine = (tid < 8);
      const unsigned* sp = gslots + (tid & 7);
      while (true){
        bool ok = true;
        if (mine) ok = (ldu(sp) >= target);
        if (__all(ok)) break;
        __builtin_amdgcn_s_sleep(1);
      }
    }
    __syncthreads();
  }
}

// ----------------------------- decoder LSTM (h-sequence only) --------------
__global__ __launch_bounds__(512) void dec_h(
    const unsigned short* __restrict__ xg,    // [64][48][2048] bf16 (bias folded)
    const unsigned short* __restrict__ whh,   // dec_Whh [2048][512] bf16
    const float* __restrict__ cbuf, unsigned long long* __restrict__ hbuf,
    unsigned short* __restrict__ X,           // [3072][1024]
    unsigned* __restrict__ slots){
  __shared__ __align__(16) unsigned short wlds[128*516];
  __shared__ __align__(16) unsigned short hblds[16*516];
  __shared__ float gbufE[256*9];
  const int tid = threadIdx.x;
  const int g = blockIdx.x & 7, j = blockIdx.x >> 3;
  const int b0 = g*8, u0 = j*64;
  for (int idx = tid; idx < 128*64; idx += 512){
    int n = idx >> 6, ch = idx & 63;
    int R = (n >> 6)*512 + u0 + (n & 63);
    *(uint4*)&wlds[n*516 + ch*8] = *(const uint4*)&whh[(size_t)R*512 + ch*8];
  }
  for (int idx = tid; idx < 1032; idx += 512)
    *(unsigned long long*)&hblds[8*516 + idx*4] = 0ull;
  const int lane = tid & 63, wv = tid >> 6, fr = lane & 15, q = lane >> 4;
  const int m = tid >> 6, j2 = tid & 63;
  bf16x8 breg[16];
  {
    int rl = 128 + wv*16 + fr;
    int R2 = (rl >> 6)*512 + u0 + (rl & 63);
    const unsigned short* wp2 = &whh[(size_t)R2*512 + q*8];
    #pragma unroll
    for (int kk = 0; kk < 16; ++kk)
      breg[kk] = *(const bf16x8*)&wp2[kk*32];
  }
  float cst = cbuf[(b0 + m)*512 + u0 + j2];
  unsigned* myslot = slots + g*16 + j;
  const unsigned* gslots = slots + g*16;
  unsigned short px0, px1, px2, px3;
  {
    size_t xi = ((size_t)(b0 + m)*48)*2048 + u0 + j2;
    px0 = xg[xi]; px1 = xg[xi + 512]; px2 = xg[xi + 1024]; px3 = xg[xi + 1536];
  }
  __syncthreads();
  for (int t = 0; t < 48; ++t){
    const int rp = t & 1, wp = rp ^ 1;
    {
      const unsigned long long* hq = hbuf + (size_t)rp*8192 + (size_t)b0*128;
      unsigned long long v0 = ldq(&hq[tid]);
      unsigned long long v1 = ldq(&hq[tid + 512]);
      int b2 = tid >> 7, q2 = tid & 127;
      *(unsigned long long*)&hblds[b2*516 + q2*4] = v0;
      *(unsigned long long*)&hblds[(b2 + 4)*516 + q2*4] = v1;
    }
    __syncthreads();
    f32x4 acc = {0.f,0.f,0.f,0.f}, acc2 = {0.f,0.f,0.f,0.f};
    #pragma unroll
    for (int kk = 0; kk < 16; ++kk){
      bf16x8 av = *(const bf16x8*)&hblds[fr*516 + kk*32 + q*8];
      bf16x8 bv = *(const bf16x8*)&wlds[(wv*16 + fr)*516 + kk*32 + q*8];
      acc  = __builtin_amdgcn_mfma_f32_16x16x32_bf16(av, bv,       acc,  0,0,0);
      acc2 = __builtin_amdgcn_mfma_f32_16x16x32_bf16(av, breg[kk], acc2, 0,0,0);
    }
    if (q < 2){
      #pragma unroll
      for (int r = 0; r < 4; ++r){
        gbufE[(wv*16 + fr)*9 + q*4 + r] = acc[r];
        gbufE[(128 + wv*16 + fr)*9 + q*4 + r] = acc2[r];
      }
    }
    __syncthreads();
    unsigned short hv;
    {
      float gi = gbufE[(j2)*9 + m]        + bf2f(px0);
      float gf = gbufE[(64 + j2)*9 + m]   + bf2f(px1);
      float gg = gbufE[(128 + j2)*9 + m]  + bf2f(px2);
      float go = gbufE[(192 + j2)*9 + m]  + bf2f(px3);
      float cc = sigm(gf)*cst + sigm(gi)*tanh2(gg);
      float hh = sigm(go)*tanh2(cc);
      cst = cc;
      hv = f2bf(hh);
      unsigned other = (unsigned)__shfl_xor((int)(unsigned)hv, 1);
      unsigned pair = ((unsigned)hv) | (other << 16);
      unsigned pair2 = (unsigned)__shfl_xor((int)pair, 2);
      if ((j2 & 3) == 0){
        unsigned long long qw = (((unsigned long long)pair2) << 32) | (unsigned long long)pair;
        stq(&hbuf[(size_t)wp*8192 + (size_t)(b0+m)*128 + ((u0 + j2) >> 2)], qw);
      }
    }
    VMWAIT();
    __syncthreads();
    if (tid == 0) stu(myslot, (unsigned)(t + 1));
    X[((size_t)t*64 + b0 + m)*1024 + u0 + j2] = hv;
    if (t < 47){
      size_t xi = ((size_t)(b0 + m)*48 + t + 1)*2048 + u0 + j2;
      px0 = xg[xi]; px1 = xg[xi + 512]; px2 = xg[xi + 1024]; px3 = xg[xi + 1536];
    }
    if (tid < 64){
      unsigned target = (unsigned)(t + 1);
      bool mine = (tid < 8);
      const unsigned* sp = gslots + (tid & 7);
      while (true){
        bool ok = true;
        if (mine) ok = (ldu(sp) >= target);
        if (__all(ok)) break;
        __builtin_amdgcn_s_sleep(1);
      }
    }
    __syncthreads();
  }
}

// ----------------------------- attention scores ----------------------------
// grid 2048 = 4 t-chunks x 64 b x 8 lc; each block does 12 t.
__global__ __launch_bounds__(256) void attn_scores(
    const unsigned short* __restrict__ encpart, // [64*512][512]
    const float* __restrict__ hwh,              // [3072][512]
    const float* __restrict__ vvec,
    float* __restrict__ scores){                // [3072][512]
  __shared__ __align__(16) float hwhs[512];
  __shared__ __align__(16) float vm2s[512];
  __shared__ float red[4];
  const int tid = threadIdx.x;
  const int tc = blockIdx.x >> 9;
  const int b = (blockIdx.x >> 3) & 63, lc = blockIdx.x & 7;
  const int l = tid >> 2, kq = tid & 3;
  const int lane = tid & 63, wv = tid >> 6;
  vm2s[tid] = -2.f * vvec[tid];
  vm2s[tid+256] = -2.f * vvec[tid+256];
  __syncthreads();
  float vsumf;
  {
    float x = vm2s[tid] + vm2s[tid+256];
    #pragma unroll
    for (int off=32; off; off>>=1) x += __shfl_xor(x, off);
    if (lane == 0) red[wv] = x;
    __syncthreads();
    vsumf = -0.5f * (red[0]+red[1]+red[2]+red[3]);
  }
  bf16x8 epr[16];
  {
    const unsigned short* ep = encpart + ((size_t)(b*512 + lc*64 + l))*512 + kq*128;
    #pragma unroll
    for (int i = 0; i < 16; ++i) epr[i] = *(const bf16x8*)&ep[i*8];
  }
  const float C = 2.88539008f;
  for (int t = tc*12; t < tc*12 + 12; ++t){
    __syncthreads();
    hwhs[tid]     = C * hwh[((size_t)t*64 + b)*512 + tid];
    hwhs[tid+256] = C * hwh[((size_t)t*64 + b)*512 + tid + 256];
    __syncthreads();
    float sacc = 0.f;
    #pragma unroll
    for (int kk = 0; kk < 16; ++kk){
      float4 h0 = *(const float4*)&hwhs[kq*128 + kk*8];
      float4 h1 = *(const float4*)&hwhs[kq*128 + kk*8 + 4];
      float4 v0 = *(const float4*)&vm2s[kq*128 + kk*8];
      float4 v1 = *(const float4*)&vm2s[kq*128 + kk*8 + 4];
      const unsigned short* e = (const unsigned short*)&epr[kk];
      float hw[8] = {h0.x,h0.y,h0.z,h0.w,h1.x,h1.y,h1.z,h1.w};
      float vv[8] = {v0.x,v0.y,v0.z,v0.w,v1.x,v1.y,v1.z,v1.w};
      #pragma unroll
      for (int ee = 0; ee < 8; ++ee){
        float a = fmaf(bf2f(e[ee]), C, hw[ee]);
        sacc = fmaf(vv[ee], __builtin_amdgcn_rcpf(1.f + __builtin_amdgcn_exp2f(a)), sacc);
      }
    }
    sacc += __shfl_xor(sacc, 1);
    sacc += __shfl_xor(sacc, 2);
    if (kq == 0) scores[((size_t)t*64 + b)*512 + lc*64 + l] = vsumf + sacc;
  }
}

// ------------------- ctx with fused softmax --------------------------------
// Each (t,b) score row is consumed by exactly one block -> softmax in-block
// with the same reduction arithmetic as the old softmax_aw (bit-identical).
__global__ __launch_bounds__(256) void ctx_k(
    const float* __restrict__ scores,           // [3072][512]
    const unsigned short* __restrict__ encout,  // [64*512][512]
    unsigned short* __restrict__ X){
  __shared__ unsigned short awt[512*12];   // [l][tt]
  __shared__ float red[4];
  const int tid = threadIdx.x;
  const int b = blockIdx.x >> 2, t0 = (blockIdx.x & 3)*12;
  const int lane = tid & 63, wv = tid >> 6;
  for (int tt = 0; tt < 12; ++tt){
    size_t row = (size_t)(t0 + tt)*64 + b;
    float v0 = scores[row*512 + tid];
    float v1 = scores[row*512 + tid + 256];
    float mx = fmaxf(v0, v1);
    #pragma unroll
    for (int off=32; off; off>>=1) mx = fmaxf(mx, __shfl_xor(mx, off));
    if (lane == 0) red[wv] = mx;
    __syncthreads();
    mx = fmaxf(fmaxf(red[0],red[1]), fmaxf(red[2],red[3]));
    __syncthreads();
    float e0 = __expf(v0 - mx), e1 = __expf(v1 - mx);
    float ps = e0 + e1;
    #pragma unroll
    for (int off=32; off; off>>=1) ps += __shfl_xor(ps, off);
    if (lane == 0) red[wv] = ps;
    __syncthreads();
    float inv = 1.f / (red[0]+red[1]+red[2]+red[3]);
    awt[tid*12 + tt]        = f2bf(e0 * inv);
    awt[(tid + 256)*12 + tt] = f2bf(e1 * inv);
    __syncthreads();
  }
  float a0[12], a1[12];
  #pragma unroll
  for (int j = 0; j < 12; ++j){ a0[j] = 0.f; a1[j] = 0.f; }
  const unsigned* eo = (const unsigned*)(encout + (size_t)b*512*512) + tid;
  for (int ll = 0; ll < 512; ++ll){
    unsigned ee = eo[(size_t)ll*256];
    float e0 = __uint_as_float((ee & 0xffffu) << 16);
    float e1 = __uint_as_float(ee & 0xffff0000u);
    const unsigned* wp2 = (const unsigned*)&awt[ll*12];
    float w[12];
    #pragma unroll
    for (int z = 0; z < 6; ++z){
      unsigned wu = wp2[z];
      w[2*z]   = bf2f((unsigned short)(wu & 0xffffu));
      w[2*z+1] = bf2f((unsigned short)(wu >> 16));
    }
    #pragma unroll
    for (int j = 0; j < 12; ++j){
      a0[j] = fmaf(w[j], e0, a0[j]);
      a1[j] = fmaf(w[j], e1, a1[j]);
    }
  }
  #pragma unroll
  for (int j = 0; j < 12; ++j){
    size_t r = (size_t)(t0+j)*64 + b;
    unsigned pk = ((unsigned)f2bf(a0[j])) | (((unsigned)f2bf(a1[j])) << 16);
    *(unsigned*)&X[r*1024 + 512 + 2*tid] = pk;
  }
}

// ----------------------------- projection ----------------------------------
__global__ void proj_k(const unsigned short* __restrict__ outs,
                       const float* __restrict__ pw, const float* __restrict__ pb,
                       float* __restrict__ out){
  int gid = blockIdx.x*256 + threadIdx.x;
  if (gid >= 64*48*7) return;
  int r = gid / 7, oc = gid % 7;
  int b = r & 63, t = r >> 6;
  const unsigned short* orow = outs + (size_t)r*512;
  const float* wrow = pw + oc*512;
  float s = pb[oc];
  for (int k = 0; k < 512; k += 8){
    bf16x8 o8 = *(const bf16x8*)&orow[k];
    #pragma unroll
    for (int e=0;e<8;e++) s += bf2f(((unsigned short*)&o8)[e]) * wrow[k+e];
  }
  out[((size_t)b*48 + t)*7 + oc] = s;
}

// ----------------------------- launch --------------------------------------
extern "C" void kernel_launch(void* const* d_in, const int* in_sizes, int n_in,
                              void* d_out, int out_size, void* d_ws, size_t ws_size,
                              hipStream_t stream){
  (void)in_sizes; (void)n_in; (void)out_size; (void)ws_size;
  const float* x_enc   = (const float*)d_in[0];
  const float* x_dec   = (const float*)d_in[1];
  const float* w_emb_e = (const float*)d_in[2];
  const float* w_emb_d = (const float*)d_in[3];
  const float* enc_Wih = (const float*)d_in[4];
  const float* enc_Whh = (const float*)d_in[5];
  const float* enc_b   = (const float*)d_in[6];
  const float* dec_Wih = (const float*)d_in[7];
  const float* dec_Whh = (const float*)d_in[8];
  const float* dec_b   = (const float*)d_in[9];
  const float* attn_W  = (const float*)d_in[10];
  const float* attn_b  = (const float*)d_in[11];
  const float* vvec    = (const float*)d_in[12];
  const float* fc_W    = (const float*)d_in[13];
  const float* fc_b    = (const float*)d_in[14];
  const float* proj_W  = (const float*)d_in[15];
  const float* proj_b  = (const float*)d_in[16];
  float* out = (float*)d_out;

  char* ws = (char*)d_ws;
  size_t off = 0;
  auto alloc = [&](size_t bytes)->char*{
    char* p = ws + off;
    off = (off + bytes + 255) & ~(size_t)255;
    return p;
  };
  unsigned short* encxw  = (unsigned short*)alloc(512ull*64*2048*2); // all steps
  unsigned short* encin  = (unsigned short*)alloc(512ull*64*512*2);  // embed; reused as enc_part
  unsigned short* encout = (unsigned short*)alloc(64ull*512*512*2);
  unsigned short* xs     = (unsigned short*)alloc(64ull*48*512*2);
  unsigned short* xg     = (unsigned short*)alloc(64ull*48*2048*2);
  unsigned short* Xb     = (unsigned short*)alloc(3072ull*1024*2);
  float* hwh    = (float*)alloc(3072ull*512*4);
  float* scores = (float*)alloc(3072ull*512*4);
  unsigned short* outsb  = (unsigned short*)alloc(3072ull*512*2);
  unsigned short* wih_e  = (unsigned short*)alloc(2048ull*512*2);
  unsigned short* whh_e  = (unsigned short*)alloc(2048ull*512*2);
  unsigned short* wih_d  = (unsigned short*)alloc(2048ull*512*2);
  unsigned short* whh_d  = (unsigned short*)alloc(2048ull*512*2);
  unsigned short* whq    = (unsigned short*)alloc(512ull*512*2);
  unsigned short* weq    = (unsigned short*)alloc(512ull*512*2);
  unsigned short* fcw    = (unsigned short*)alloc(512ull*1024*2);
  unsigned long long* hbuf = (unsigned long long*)alloc(2ull*64*128*8);
  float* cbuf   = (float*)alloc(64ull*512*4);
  unsigned* eslots = (unsigned*)alloc(4*64*4);
  unsigned* dslots = (unsigned*)alloc(4*64*4);

  hipMemsetAsync(hbuf, 0, 2ull*64*128*8, stream);
  hipMemsetAsync(cbuf, 0, 64ull*512*4, stream);
  hipMemsetAsync(eslots, 0, 4*64*4, stream);
  hipMemsetAsync(dslots, 0, 4*64*4, stream);

  // merged prep: embeds + all weight casts (10304 blocks x 512)
  prep_k<<<10304, 512, 0, stream>>>(x_enc, x_dec, w_emb_e, w_emb_d, encin, xs,
                                    enc_Wih, enc_Whh, dec_Wih, dec_Whh, fc_W, attn_W,
                                    wih_e, whh_e, wih_d, whh_d, fcw, whq, weq);

  // merged staging GEMM (encxw) + xg gemm64 (4864 blocks)
  gemm_pair_k<<<4864, 256, 0, stream>>>(encin, wih_e, enc_b, encxw,
                                        xs, wih_d, dec_b, xg);

  // ONE persistent lstm launch, 512 steps (8 groups x 8 unit-blocks)
  lstm_enc<<<64, 512, 0, stream>>>(encxw, whh_e, cbuf, hbuf, encout, 0, 512, eslots);

  // enc_part = encout @ We^T + attn_b  (reuses encin buffer)
  gemm_nt<<<dim3(4, 256), 256, 0, stream>>>(encout, 512, weq, 512, attn_b, encin, 512, 32768, 512, 512);

  // decoder LSTM h-sequence -> X[:, :512]
  dec_h<<<64, 512, 0, stream>>>(xg, whh_d, cbuf, hbuf, Xb, dslots);

  // hWh = h @ Wh^T  (f32)  (64-row tiles, 192 blocks)
  gemm64_ntf<<<dim3(4, 48), 256, 0, stream>>>(Xb, 1024, whq, 512, hwh, 512, 3072, 512, 512);

  // scores (4x t-parallel), then ctx with fused softmax
  attn_scores<<<2048, 256, 0, stream>>>(encin /*enc_part*/, hwh, vvec, scores);
  ctx_k<<<256, 256, 0, stream>>>(scores, encout, Xb);

  // fc: [h|ctx] @ fc_W^T + fc_b  (64-row tiles, 192 blocks)
  gemm64_nt<<<dim3(4, 48), 256, 0, stream>>>(Xb, 1024, fcw, 1024, fc_b, outsb, 512, 3072, 512, 1024);

  proj_k<<<84, 256, 0, stream>>>(outsb, proj_W, proj_b, out);
}